// Round 5
// baseline (374.715 us; speedup 1.0000x reference)
//
#include <hip/hip_runtime.h>

#define N_EDGES_C 1048576

typedef __attribute__((ext_vector_type(8))) __bf16 bf16x8;
typedef __attribute__((ext_vector_type(4))) __bf16 bf16x4;
typedef __attribute__((ext_vector_type(4))) float f32x4;
typedef __attribute__((ext_vector_type(4))) unsigned short us4;

#define MFMA16(a,b,c) __builtin_amdgcn_mfma_f32_16x16x32_bf16((a),(b),(c),0,0,0)

__device__ __forceinline__ unsigned short f2bf(float f) {
  unsigned int u = __builtin_bit_cast(unsigned int, f);
  u = (u + 0x7fffu + ((u >> 16) & 1u)) >> 16;
  return (unsigned short)u;
}

// global weights, [N][K] layout (B^T), K contiguous, no padding
__device__ __forceinline__ bf16x8 fragG(const unsigned short* p, int K, int nc, int kb, int lane) {
  return *(const bf16x8*)(p + (nc + (lane & 15)) * K + kb + ((lane >> 4) << 3));
}
// swizzled 128x128 bf16 LDS tile (row stride 256B, byte ^= (row&7)<<4)
__device__ __forceinline__ bf16x8 fragM(const unsigned short* sM, int row, int kb, int lane) {
  int r = row + (lane & 15);
  int cb = (kb + ((lane >> 4) << 3)) * 2;
  return *(const bf16x8*)((const char*)sM + r * 256 + (cb ^ ((r & 7) << 4)));
}
__device__ __forceinline__ void putBf(unsigned short* sM, int r, int c, float v) {
  *(__bf16*)((char*)sM + r * 256 + ((c * 2) ^ ((r & 7) << 4))) = (__bf16)v;
}
// pair region: 64-row tiles, row stride 128B, same XOR swizzle
__device__ __forceinline__ bf16x8 fragP(const unsigned short* sP, int row, int kb, int lane) {
  int r = row + (lane & 15);
  int cb = (kb + ((lane >> 4) << 3)) * 2;
  return *(const bf16x8*)((const char*)sP + r * 128 + (cb ^ ((r & 7) << 4)));
}
__device__ __forceinline__ void putP(unsigned short* sP, int r, int c, float v) {
  *(__bf16*)((char*)sP + r * 128 + ((c * 2) ^ ((r & 7) << 4))) = (__bf16)v;
}
// Adj counts: u8 [128][128], row stride 128B, byte col ^= (row&7)<<3
// register-only decode; inv (row 1/deg) hoisted by caller — per-lane constant per layer
__device__ __forceinline__ bf16x8 adjFrag(const unsigned char* sCc, float inv,
                                          int mBase, int kb, int lane) {
  int m = mBase + (lane & 15);
  int c = (kb + ((lane >> 4) << 3)) ^ ((m & 7) << 3);
  const unsigned int* p = (const unsigned int*)(sCc + m * 128 + c);
  unsigned int w0 = p[0], w1 = p[1];
  bf16x8 r;
#pragma unroll
  for (int i = 0; i < 4; i++) {
    r[i]     = (__bf16)((float)((w0 >> (8 * i)) & 0xffu) * inv);
    r[4 + i] = (__bf16)((float)((w1 >> (8 * i)) & 0xffu) * inv);
  }
  return r;
}

// ---------------- prep: bf16-transpose weights + fold BN + transpose readout W ----------------
__global__ void prep_kernel(const float* __restrict__ Wc0s, const float* __restrict__ Wc0n,
                            const float* __restrict__ Wc1s, const float* __restrict__ Wc1n,
                            const float* __restrict__ Wa,
                            const float* __restrict__ bc0, const float* __restrict__ g0,
                            const float* __restrict__ b0, const float* __restrict__ m0,
                            const float* __restrict__ v0,
                            const float* __restrict__ bc1, const float* __restrict__ g1,
                            const float* __restrict__ b1, const float* __restrict__ m1,
                            const float* __restrict__ v1,
                            const float* __restrict__ Wr0, const float* __restrict__ Wr1,
                            unsigned short* __restrict__ wbf, float* __restrict__ cst,
                            float* __restrict__ wr0t, float* __restrict__ wr1t) {
  int t = blockIdx.x * blockDim.x + threadIdx.x;
  if (t < 8192) {                       // 64x128 -> [d][f]
    int d = t >> 6, f = t & 63;
    wbf[t]        = f2bf(Wc0s[f * 128 + d]);
    wbf[8192 + t] = f2bf(Wc0n[f * 128 + d]);
  } else if (t < 24576) {               // 128x128 -> [d][k]
    int i = t - 8192;
    int d = i >> 7, k = i & 127;
    wbf[16384 + i] = f2bf(Wc1s[k * 128 + d]);
    wbf[32768 + i] = f2bf(Wc1n[k * 128 + d]);
    wbf[49152 + i] = f2bf(Wa[k * 128 + d]);
  } else if (t < 24704) {
    int d = t - 24576;
    float s0 = g0[d] * rsqrtf(v0[d] + 1e-5f);
    cst[d]       = s0;
    cst[128 + d] = (bc0[d] - m0[d]) * s0 + b0[d];
    float s1 = g1[d] * rsqrtf(v1[d] + 1e-5f);
    cst[256 + d] = s1;
    cst[384 + d] = (bc1[d] - m1[d]) * s1 + b1[d];
  } else if (t < 57472) {               // readout weights f32 transpose: wrT[d][j] = Wr[j][d]
    int i = t - 24704;
    int which = i >> 14;
    int k = i & 16383;
    int d = k >> 7, j = k & 127;
    float v = (which ? Wr1 : Wr0)[j * 128 + d];
    (which ? wr1t : wr0t)[k] = v;
  }
}

// ---------------- fused per-graph kernel: 1 block = 1 graph, ~50KB LDS, 3 blocks/CU ----------------
// 2nd launch_bounds arg is BLOCKS/CU on this hipcc (R2/R3/R4 VGPR evidence:
// 4 -> 64 VGPR = 512/8waves, 6 -> 40 VGPR = 512/12waves). 3 -> cap ~84, LDS allows exactly 3.
__global__ __launch_bounds__(512, 3)
void gnn_fused(const float* __restrict__ x, const float* __restrict__ mwt,
               const int* __restrict__ ei,
               const unsigned short* __restrict__ wbf, const float* __restrict__ cst,
               const float* __restrict__ ba,
               const float* __restrict__ wr0t, const float* __restrict__ br0,
               const float* __restrict__ wr1t, const float* __restrict__ br1,
               const float* __restrict__ Wout, const float* __restrict__ bout,
               float* __restrict__ out) {
  __shared__ unsigned short sM[128 * 128];   // 32KB: x / V^T / h / p (swizzled)
  __shared__ unsigned char  sC[128 * 128];   // 16KB: Adj u8 counts -> pair+pairT bf16
  __shared__ float sInv[128];
  __shared__ float sPool[128];
  __shared__ float sV1[128];
  __shared__ float sOut;

  const int g = blockIdx.x;
  const int t = threadIdx.x;
  const int lane = t & 63;
  const int w = t >> 6;              // wave 0..7
  const int col = lane & 15;
  const int r0 = (lane >> 4) << 2;
  const f32x4 zero = {0.f, 0.f, 0.f, 0.f};

  // ---- P0a: zero counts + pool
  {
    unsigned int* c32 = (unsigned int*)sC;
    for (int i = t; i < 4096; i += 512) c32[i] = 0u;
    if (t < 128) sPool[t] = 0.f;
    if (t == 0) sOut = 0.f;
  }
  __syncthreads();

  // ---- P0b: edge histogram (swizzled u8 grid) + x -> sM (bf16, swizzled)
  {
    int e = g * 512 + t;
    int ls_ = ei[e] & 127;
    int ld_ = ei[N_EDGES_C + e] & 127;
    int cb = ls_ ^ ((ld_ & 7) << 3);
    int idx = ld_ * 128 + cb;
    atomicAdd((unsigned int*)(sC + (idx & ~3)), 1u << ((idx & 3) * 8));
  }
  {
    const float4* xg = (const float4*)(x + (size_t)g * 8192);
#pragma unroll
    for (int i = 0; i < 4; i++) {
      int vi = t + i * 512;
      float4 v = xg[vi];
      int node = vi >> 4;
      int f = (vi & 15) * 4;
      bf16x4 q = {(__bf16)v.x, (__bf16)v.y, (__bf16)v.z, (__bf16)v.w};
      *(bf16x4*)((char*)sM + node * 256 + ((f * 2) ^ ((node & 7) << 4))) = q;
    }
  }
  __syncthreads();

  // ---- P0c: inv_deg row sums, 4 threads/row (swizzle permutes within row -> sum invariant)
  {
    int row = t >> 2, q = t & 3;
    const unsigned int* rp = (const unsigned int*)(sC + row * 128) + q * 8;
    int ssum = 0;
#pragma unroll
    for (int i = 0; i < 8; i++) {
      unsigned int v = rp[i];
      ssum += (int)(v & 0xff) + (int)((v >> 8) & 0xff) + (int)((v >> 16) & 0xff) + (int)(v >> 24);
    }
    ssum += __shfl_xor(ssum, 1);
    ssum += __shfl_xor(ssum, 2);
    if (q == 0) sInv[row] = 1.f / (float)(ssum > 1 ? ssum : 1);
  }

  f32x4 acc[8];

  // ================= Layer 0 (K_in = 64) =================
  {
    bf16x8 xA[2];
#pragma unroll
    for (int kb = 0; kb < 2; kb++) xA[kb] = fragM(sM, w * 16, kb * 32, lane);
#pragma unroll
    for (int n = 0; n < 8; n++) acc[n] = zero;
    for (int kb = 0; kb < 2; kb++)
#pragma unroll
      for (int n = 0; n < 8; n++)
        acc[n] = MFMA16(xA[kb], fragG(wbf + 8192, 64, n * 16, kb * 32, lane), acc[n]);  // V0 = x@W0n
    __syncthreads();  // all preloads (and sInv) done before V^T overwrites x
    const float invRow = sInv[w * 16 + col];  // hoisted for adjFrag (per-lane row 1/deg)
#pragma unroll
    for (int n = 0; n < 8; n++) {  // write V0^T[d][node]
      bf16x4 q = {(__bf16)acc[n][0], (__bf16)acc[n][1], (__bf16)acc[n][2], (__bf16)acc[n][3]};
      int d = n * 16 + col;
      *(bf16x4*)((char*)sM + d * 256 + (((w * 16 + r0) * 2) ^ ((d & 7) << 4))) = q;
    }
    __syncthreads();
#pragma unroll
    for (int n = 0; n < 8; n++) acc[n] = zero;
    for (int kb = 0; kb < 2; kb++)
#pragma unroll
      for (int n = 0; n < 8; n++)
        acc[n] = MFMA16(xA[kb], fragG(wbf, 64, n * 16, kb * 32, lane), acc[n]);         // + x@W0s
    for (int kb = 0; kb < 4; kb++) {
      bf16x8 aF = adjFrag(sC, invRow, w * 16, kb * 32, lane);
#pragma unroll
      for (int n = 0; n < 8; n++)
        acc[n] = MFMA16(aF, fragM(sM, n * 16, kb * 32, lane), acc[n]);                  // + Adjn@V0
    }
    __syncthreads();  // all V0^T reads done before h1 writes
#pragma unroll
    for (int n = 0; n < 8; n++) {  // BN0 + leaky -> h1[node][d]
      int d = n * 16 + col;
      float mul = cst[d], add = cst[128 + d];
#pragma unroll
      for (int r = 0; r < 4; r++) {
        float v = acc[n][r] * mul + add;
        v = v > 0.f ? v : 0.01f * v;
        putBf(sM, w * 16 + r0 + r, d, v);
      }
    }
    // no barrier: next phase preloads only this wave's own rows
  }

  // ================= Layer 1 (K = 128) =================
  {
    bf16x8 hA[4];
#pragma unroll
    for (int kb = 0; kb < 4; kb++) hA[kb] = fragM(sM, w * 16, kb * 32, lane);
#pragma unroll
    for (int n = 0; n < 8; n++) acc[n] = zero;
    for (int kb = 0; kb < 4; kb++)
#pragma unroll
      for (int n = 0; n < 8; n++)
        acc[n] = MFMA16(hA[kb], fragG(wbf + 32768, 128, n * 16, kb * 32, lane), acc[n]); // V1 = h1@W1n
    __syncthreads();
    const float invRow = sInv[w * 16 + col];
#pragma unroll
    for (int n = 0; n < 8; n++) {
      bf16x4 q = {(__bf16)acc[n][0], (__bf16)acc[n][1], (__bf16)acc[n][2], (__bf16)acc[n][3]};
      int d = n * 16 + col;
      *(bf16x4*)((char*)sM + d * 256 + (((w * 16 + r0) * 2) ^ ((d & 7) << 4))) = q;
    }
    __syncthreads();
#pragma unroll
    for (int n = 0; n < 8; n++) acc[n] = zero;
    for (int kb = 0; kb < 4; kb++)
#pragma unroll
      for (int n = 0; n < 8; n++)
        acc[n] = MFMA16(hA[kb], fragG(wbf + 16384, 128, n * 16, kb * 32, lane), acc[n]); // + h1@W1s
    for (int kb = 0; kb < 4; kb++) {
      bf16x8 aF = adjFrag(sC, invRow, w * 16, kb * 32, lane);
#pragma unroll
      for (int n = 0; n < 8; n++)
        acc[n] = MFMA16(aF, fragM(sM, n * 16, kb * 32, lane), acc[n]);                   // + Adjn@V1
    }
    float mwr[4];
#pragma unroll
    for (int r = 0; r < 4; r++) mwr[r] = mwt[(size_t)g * 128 + w * 16 + r0 + r];
    __syncthreads();  // all V1^T reads done before h2 writes
#pragma unroll
    for (int n = 0; n < 8; n++) {  // BN1 + leaky + *mw -> h2; fold residual into pool
      int d = n * 16 + col;
      float mul = cst[256 + d], add = cst[384 + d];
      float csum = 0.f;
#pragma unroll
      for (int r = 0; r < 4; r++) {
        float v = acc[n][r] * mul + add;
        v = v > 0.f ? v : 0.01f * v;
        v *= mwr[r];
        putBf(sM, w * 16 + r0 + r, d, v);
        csum += v;
      }
      csum += __shfl_xor(csum, 16);
      csum += __shfl_xor(csum, 32);
      if (lane < 16) atomicAdd(&sPool[d], csum);
    }
    // no barrier: P3 preloads only own rows
  }

  // ---- P3: p = leaky(h2@Wa + ba) -> overwrite own rows of sM
  {
    bf16x8 hA[4];
#pragma unroll
    for (int kb = 0; kb < 4; kb++) hA[kb] = fragM(sM, w * 16, kb * 32, lane);
#pragma unroll
    for (int n = 0; n < 8; n++) acc[n] = zero;
    for (int kb = 0; kb < 4; kb++)
#pragma unroll
      for (int n = 0; n < 8; n++)
        acc[n] = MFMA16(hA[kb], fragG(wbf + 49152, 128, n * 16, kb * 32, lane), acc[n]);
#pragma unroll
    for (int n = 0; n < 8; n++) {
      int d = n * 16 + col;
      float bav = ba[d];
#pragma unroll
      for (int r = 0; r < 4; r++) {
        float v = acc[n][r] + bav;
        v = v > 0.f ? v : 0.01f * v;
        putBf(sM, w * 16 + r0 + r, d, v);
      }
    }
  }
  __syncthreads();  // p complete for all rows

  // ---- P6: pair = sigmoid(pA@pB^T) -> sC (counts dead): pair[0..63], pairT at +4096
  {
    unsigned short* sP = (unsigned short*)sC;
    f32x4 acc2[2] = {zero, zero};
    for (int kb = 0; kb < 128; kb += 32) {
#pragma unroll
      for (int i = 0; i < 2; i++) {
        int T = w * 2 + i;
        bf16x8 a = fragM(sM, (T >> 2) * 16, kb, lane);
        bf16x8 b = fragM(sM, 64 + (T & 3) * 16, kb, lane);
        acc2[i] = MFMA16(a, b, acc2[i]);
      }
    }
#pragma unroll
    for (int i = 0; i < 2; i++) {
      int T = w * 2 + i, mb = (T >> 2) * 16, nb = (T & 3) * 16;
#pragma unroll
      for (int r = 0; r < 4; r++) {
        float v = 1.f / (1.f + __expf(-acc2[i][r]));
        putP(sP, mb + r0 + r, nb + col, v);
        putP(sP + 4096, nb + col, mb + r0 + r, v);
      }
    }
  }

  // ---- Ptr: in-place transpose of p (4x4 u16 blocks, 2 per thread)
  {
    us4 rd[2][4];
#pragma unroll
    for (int b = 0; b < 2; b++) {
      int id = t + b * 512, R = id >> 5, C = id & 31;
#pragma unroll
      for (int j = 0; j < 4; j++) {
        int r = 4 * R + j;
        rd[b][j] = *(const us4*)((const char*)sM + r * 256 + ((C * 8) ^ ((r & 7) << 4)));
      }
    }
    __syncthreads();  // all p reads (P6 MFMAs + block reads) done
#pragma unroll
    for (int b = 0; b < 2; b++) {
      int id = t + b * 512, R = id >> 5, C = id & 31;
#pragma unroll
      for (int cc = 0; cc < 4; cc++) {
        us4 o = {rd[b][0][cc], rd[b][1][cc], rd[b][2][cc], rd[b][3][cc]};
        int r = 4 * C + cc;
        *(us4*)((char*)sM + r * 256 + ((R * 8) ^ ((r & 7) << 4))) = o;
      }
    }
  }
  __syncthreads();

  // ---- P7: newA_delta = pair@pB (w0-3) / newB_delta = pairT@pA (w4-7) -> pool only
  {
    const unsigned short* sP = (const unsigned short*)sC;
    const int isB = w >> 2;
    const int mr = (w & 3) * 16;
#pragma unroll
    for (int n = 0; n < 8; n++) acc[n] = zero;
    for (int kb = 0; kb < 64; kb += 32) {
      bf16x8 a = fragP(sP + (isB ? 4096 : 0), mr, kb, lane);
      int koff = isB ? kb : 64 + kb;
#pragma unroll
      for (int n = 0; n < 8; n++) {
        bf16x8 bfr = fragM(sM, n * 16, koff, lane);  // p^T[d][node]
        acc[n] = MFMA16(a, bfr, acc[n]);
      }
    }
#pragma unroll
    for (int n = 0; n < 8; n++) {
      int d = n * 16 + col;
      float csum = acc[n][0] + acc[n][1] + acc[n][2] + acc[n][3];
      csum += __shfl_xor(csum, 16);
      csum += __shfl_xor(csum, 32);
      if (lane < 16) atomicAdd(&sPool[d], csum);
    }
  }
  __syncthreads();

  // ---- P8: readout (transposed f32 weights: contiguous per-thread rows)
  if (t < 128) sPool[t] *= (1.f / 128.f);
  __syncthreads();
  {
    int d = t >> 2, q = t & 3;
    const float* row = wr0t + d * 128 + q * 32;
    float s = 0.f;
#pragma unroll
    for (int j = 0; j < 32; j++) s += sPool[q * 32 + j] * row[j];
    s += __shfl_xor(s, 1);
    s += __shfl_xor(s, 2);
    if (q == 0) { s += br0[d]; sV1[d] = s > 0.f ? s : 0.01f * s; }
  }
  __syncthreads();
  {
    int d = t >> 2, q = t & 3;
    const float* row = wr1t + d * 128 + q * 32;
    float s = 0.f;
#pragma unroll
    for (int j = 0; j < 32; j++) s += sV1[q * 32 + j] * row[j];
    s += __shfl_xor(s, 1);
    s += __shfl_xor(s, 2);
    if (q == 0) { s += br1[d]; sPool[d] = s > 0.f ? s : 0.01f * s; }
  }
  __syncthreads();
  if (t < 128) atomicAdd(&sOut, sPool[t] * Wout[t]);
  __syncthreads();
  if (t == 0) out[g] = sOut + bout[0];
}

extern "C" void kernel_launch(void* const* d_in, const int* in_sizes, int n_in,
                              void* d_out, int out_size, void* d_ws, size_t ws_size,
                              hipStream_t stream) {
  const float* x     = (const float*)d_in[0];
  const float* mwt   = (const float*)d_in[1];
  const float* Wc0s  = (const float*)d_in[2];
  const float* Wc0n  = (const float*)d_in[3];
  const float* bc0   = (const float*)d_in[4];
  const float* g0    = (const float*)d_in[5];
  const float* b0    = (const float*)d_in[6];
  const float* m0    = (const float*)d_in[7];
  const float* v0    = (const float*)d_in[8];
  const float* Wc1s  = (const float*)d_in[9];
  const float* Wc1n  = (const float*)d_in[10];
  const float* bc1   = (const float*)d_in[11];
  const float* g1    = (const float*)d_in[12];
  const float* b1    = (const float*)d_in[13];
  const float* m1    = (const float*)d_in[14];
  const float* v1    = (const float*)d_in[15];
  const float* Wa    = (const float*)d_in[16];
  const float* ba    = (const float*)d_in[17];
  const float* Wr0   = (const float*)d_in[18];
  const float* br0   = (const float*)d_in[19];
  const float* Wr1   = (const float*)d_in[20];
  const float* br1   = (const float*)d_in[21];
  const float* Wout  = (const float*)d_in[22];
  const float* bout  = (const float*)d_in[23];
  const int*   ei    = (const int*)d_in[24];

  unsigned short* wbf = (unsigned short*)d_ws;                 // 131072 B
  float* cst  = (float*)((char*)d_ws + 131072);                // 2048 B
  float* wr0t = (float*)((char*)d_ws + 133120);                // 65536 B
  float* wr1t = (float*)((char*)d_ws + 198656);                // 65536 B

  prep_kernel<<<dim3(225), dim3(256), 0, stream>>>(Wc0s, Wc0n, Wc1s, Wc1n, Wa,
                                                   bc0, g0, b0, m0, v0,
                                                   bc1, g1, b1, m1, v1,
                                                   Wr0, Wr1, wbf, cst, wr0t, wr1t);
  gnn_fused<<<dim3(2048), dim3(512), 0, stream>>>(x, mwt, ei, wbf, cst, ba,
                                                  wr0t, br0, wr1t, br1, Wout, bout,
                                                  (float*)d_out);
}

// Round 6
// 163.240 us; speedup vs baseline: 2.2955x; 2.2955x over previous
//
#include <hip/hip_runtime.h>

#define N_EDGES_C 1048576

typedef __attribute__((ext_vector_type(8))) __bf16 bf16x8;
typedef __attribute__((ext_vector_type(4))) __bf16 bf16x4;
typedef __attribute__((ext_vector_type(4))) float f32x4;
typedef __attribute__((ext_vector_type(4))) unsigned short us4;
typedef __attribute__((ext_vector_type(4))) unsigned int u32x4;

#define MFMA16(a,b,c) __builtin_amdgcn_mfma_f32_16x16x32_bf16((a),(b),(c),0,0,0)

__device__ __forceinline__ unsigned short f2bf(float f) {
  unsigned int u = __builtin_bit_cast(unsigned int, f);
  u = (u + 0x7fffu + ((u >> 16) & 1u)) >> 16;
  return (unsigned short)u;
}

// swizzled 128x128 bf16 LDS tile (row stride 256B, byte ^= (row&7)<<4)
__device__ __forceinline__ bf16x8 fragM(const unsigned short* sM, int row, int kb, int lane) {
  int r = row + (lane & 15);
  int cb = (kb + ((lane >> 4) << 3)) * 2;
  return *(const bf16x8*)((const char*)sM + r * 256 + (cb ^ ((r & 7) << 4)));
}
__device__ __forceinline__ void putBf(unsigned short* sM, int r, int c, float v) {
  *(__bf16*)((char*)sM + r * 256 + ((c * 2) ^ ((r & 7) << 4))) = (__bf16)v;
}
// weight chunk in LDS: [128 rows][64 k] u16, row stride 128B, byte ^= (row&7)<<4
__device__ __forceinline__ bf16x8 fragW(const unsigned short* sW, int nc, int kk, int lane) {
  int r = nc + (lane & 15);
  int cb = (kk + ((lane >> 4) << 3)) * 2;
  return *(const bf16x8*)((const char*)sW + r * 128 + (cb ^ ((r & 7) << 4)));
}
// pair region: 64-row tiles, row stride 128B, same XOR swizzle
__device__ __forceinline__ bf16x8 fragP(const unsigned short* sP, int row, int kb, int lane) {
  int r = row + (lane & 15);
  int cb = (kb + ((lane >> 4) << 3)) * 2;
  return *(const bf16x8*)((const char*)sP + r * 128 + (cb ^ ((r & 7) << 4)));
}
__device__ __forceinline__ void putP(unsigned short* sP, int r, int c, float v) {
  *(__bf16*)((char*)sP + r * 128 + ((c * 2) ^ ((r & 7) << 4))) = (__bf16)v;
}
// Adj counts: u8 [128][128], row stride 128B, byte col ^= (row&7)<<3 (register-only decode)
__device__ __forceinline__ bf16x8 adjFrag(const unsigned char* sCc, float inv,
                                          int mBase, int kb, int lane) {
  int m = mBase + (lane & 15);
  int c = (kb + ((lane >> 4) << 3)) ^ ((m & 7) << 3);
  const unsigned int* p = (const unsigned int*)(sCc + m * 128 + c);
  unsigned int w0 = p[0], w1 = p[1];
  bf16x8 r;
#pragma unroll
  for (int i = 0; i < 4; i++) {
    r[i]     = (__bf16)((float)((w0 >> (8 * i)) & 0xffu) * inv);
    r[4 + i] = (__bf16)((float)((w1 >> (8 * i)) & 0xffu) * inv);
  }
  return r;
}

// stage helpers: chunk = [128 rows][64 k] u16 (16KB). Loads issued early (regs),
// ds_write after the barrier that frees the buffer.
__device__ __forceinline__ void stG(const unsigned short* src, int rowK, int kOff, int t,
                                    u32x4& a, u32x4& b) {
  int i1 = t + 512;
  a = *(const u32x4*)(src + (t >> 3) * rowK + kOff + (t & 7) * 8);
  b = *(const u32x4*)(src + (i1 >> 3) * rowK + kOff + (i1 & 7) * 8);
}
__device__ __forceinline__ void stW(unsigned short* sW, int t, u32x4 a, u32x4 b) {
  int i1 = t + 512;
  *(u32x4*)((char*)sW + (t  >> 3) * 128 + (((t  & 7) * 16) ^ (((t  >> 3) & 7) << 4))) = a;
  *(u32x4*)((char*)sW + (i1 >> 3) * 128 + (((i1 & 7) * 16) ^ (((i1 >> 3) & 7) << 4))) = b;
}

// ---------------- prep: bf16-transpose weights + fold BN + transpose readout W ----------------
__global__ void prep_kernel(const float* __restrict__ Wc0s, const float* __restrict__ Wc0n,
                            const float* __restrict__ Wc1s, const float* __restrict__ Wc1n,
                            const float* __restrict__ Wa,
                            const float* __restrict__ bc0, const float* __restrict__ g0,
                            const float* __restrict__ b0, const float* __restrict__ m0,
                            const float* __restrict__ v0,
                            const float* __restrict__ bc1, const float* __restrict__ g1,
                            const float* __restrict__ b1, const float* __restrict__ m1,
                            const float* __restrict__ v1,
                            const float* __restrict__ Wr0, const float* __restrict__ Wr1,
                            unsigned short* __restrict__ wbf, float* __restrict__ cst,
                            float* __restrict__ wr0t, float* __restrict__ wr1t) {
  int t = blockIdx.x * blockDim.x + threadIdx.x;
  if (t < 8192) {                       // 64x128 -> [d][f]
    int d = t >> 6, f = t & 63;
    wbf[t]        = f2bf(Wc0s[f * 128 + d]);
    wbf[8192 + t] = f2bf(Wc0n[f * 128 + d]);
  } else if (t < 24576) {               // 128x128 -> [d][k]
    int i = t - 8192;
    int d = i >> 7, k = i & 127;
    wbf[16384 + i] = f2bf(Wc1s[k * 128 + d]);
    wbf[32768 + i] = f2bf(Wc1n[k * 128 + d]);
    wbf[49152 + i] = f2bf(Wa[k * 128 + d]);
  } else if (t < 24704) {
    int d = t - 24576;
    float s0 = g0[d] * rsqrtf(v0[d] + 1e-5f);
    cst[d]       = s0;
    cst[128 + d] = (bc0[d] - m0[d]) * s0 + b0[d];
    float s1 = g1[d] * rsqrtf(v1[d] + 1e-5f);
    cst[256 + d] = s1;
    cst[384 + d] = (bc1[d] - m1[d]) * s1 + b1[d];
  } else if (t < 57472) {               // readout weights f32 transpose
    int i = t - 24704;
    int which = i >> 14;
    int k = i & 16383;
    int d = k >> 7, j = k & 127;
    float v = (which ? Wr1 : Wr0)[j * 128 + d];
    (which ? wr1t : wr0t)[k] = v;
  }
}

// ---------------- fused per-graph kernel: 1 block = 1 graph, ~66KB LDS, 2 blocks/CU ----------------
__global__ __launch_bounds__(512, 4)
void gnn_fused(const float* __restrict__ x, const float* __restrict__ mwt,
               const int* __restrict__ ei,
               const unsigned short* __restrict__ wbf, const float* __restrict__ cst,
               const float* __restrict__ ba,
               const float* __restrict__ wr0t, const float* __restrict__ br0,
               const float* __restrict__ wr1t, const float* __restrict__ br1,
               const float* __restrict__ Wout, const float* __restrict__ bout,
               float* __restrict__ out) {
  __shared__ unsigned short sM[128 * 128];   // 32KB: x / V^T / h / p (swizzled)
  __shared__ unsigned char  sC[128 * 128];   // 16KB: Adj u8 counts -> pair+pairT bf16
  __shared__ unsigned short sW[8192];        // 16KB: staged weight chunk [128][64]
  __shared__ float sInv[128];
  __shared__ float sPool[128];
  __shared__ float sV1[128];
  __shared__ float sOut;

  const int g = blockIdx.x;
  const int t = threadIdx.x;
  const int lane = t & 63;
  const int w = t >> 6;              // wave 0..7
  const int col = lane & 15;
  const int r0 = (lane >> 4) << 2;
  const f32x4 zero = {0.f, 0.f, 0.f, 0.f};
  u32x4 sa, sb;                      // in-flight stage regs

  // ---- S0: issue c0 (W0n) loads; zero counts+pool; x -> sM (bf16, swizzled)
  stG(wbf + 8192, 64, 0, t, sa, sb);
  {
    unsigned int* c32 = (unsigned int*)sC;
    for (int i = t; i < 4096; i += 512) c32[i] = 0u;
    if (t < 128) sPool[t] = 0.f;
    if (t == 0) sOut = 0.f;
  }
  {
    const float4* xg = (const float4*)(x + (size_t)g * 8192);
#pragma unroll
    for (int i = 0; i < 4; i++) {
      int vi = t + i * 512;
      float4 v = xg[vi];
      int node = vi >> 4;
      int f = (vi & 15) * 4;
      bf16x4 q = {(__bf16)v.x, (__bf16)v.y, (__bf16)v.z, (__bf16)v.w};
      *(bf16x4*)((char*)sM + node * 256 + ((f * 2) ^ ((node & 7) << 4))) = q;
    }
  }
  __syncthreads();

  // ---- S1: edge histogram + xA preload
  {
    int e = g * 512 + t;
    int ls_ = ei[e] & 127;
    int ld_ = ei[N_EDGES_C + e] & 127;
    int cb = ls_ ^ ((ld_ & 7) << 3);
    int idx = ld_ * 128 + cb;
    atomicAdd((unsigned int*)(sC + (idx & ~3)), 1u << ((idx & 3) * 8));
  }
  bf16x8 xA0 = fragM(sM, w * 16, 0, lane);
  bf16x8 xA1 = fragM(sM, w * 16, 32, lane);
  __syncthreads();

  // ---- S2: commit c0; inv_deg row sums (4 threads/row)
  stW(sW, t, sa, sb);
  {
    int row = t >> 2, q = t & 3;
    const unsigned int* rp = (const unsigned int*)(sC + row * 128) + q * 8;
    int ssum = 0;
#pragma unroll
    for (int i = 0; i < 8; i++) {
      unsigned int v = rp[i];
      ssum += (int)(v & 0xff) + (int)((v >> 8) & 0xff) + (int)((v >> 16) & 0xff) + (int)(v >> 24);
    }
    ssum += __shfl_xor(ssum, 1);
    ssum += __shfl_xor(ssum, 2);
    if (q == 0) sInv[row] = 1.f / (float)(ssum > 1 ? ssum : 1);
  }
  __syncthreads();

  f32x4 acc[8];

  // ---- S3: V0 = x @ W0n (c0); issue c1 (W0s); write V0^T
  stG(wbf, 64, 0, t, sa, sb);
#pragma unroll
  for (int n = 0; n < 8; n++) acc[n] = zero;
#pragma unroll
  for (int n = 0; n < 8; n++) acc[n] = MFMA16(xA0, fragW(sW, n * 16, 0, lane), acc[n]);
#pragma unroll
  for (int n = 0; n < 8; n++) acc[n] = MFMA16(xA1, fragW(sW, n * 16, 32, lane), acc[n]);
#pragma unroll
  for (int n = 0; n < 8; n++) {  // V0^T[d][node]
    bf16x4 q = {(__bf16)acc[n][0], (__bf16)acc[n][1], (__bf16)acc[n][2], (__bf16)acc[n][3]};
    int d = n * 16 + col;
    *(bf16x4*)((char*)sM + d * 256 + (((w * 16 + r0) * 2) ^ ((d & 7) << 4))) = q;
  }
  __syncthreads();

  // ---- S4: commit c1; acc = Adj @ V0 (no weights) — overlaps ds_write latency
  stW(sW, t, sa, sb);
#pragma unroll
  for (int n = 0; n < 8; n++) acc[n] = zero;
  {
    const float invRow = sInv[w * 16 + col];
    for (int kb = 0; kb < 4; kb++) {
      bf16x8 aF = adjFrag(sC, invRow, w * 16, kb * 32, lane);
#pragma unroll
      for (int n = 0; n < 8; n++)
        acc[n] = MFMA16(aF, fragM(sM, n * 16, kb * 32, lane), acc[n]);
    }
  }
  __syncthreads();

  // ---- S5: acc += x @ W0s (c1); BN0+leaky -> h1 rows; hA preload; issue c2 (W1n a)
  stG(wbf + 32768, 128, 0, t, sa, sb);
#pragma unroll
  for (int n = 0; n < 8; n++) acc[n] = MFMA16(xA0, fragW(sW, n * 16, 0, lane), acc[n]);
#pragma unroll
  for (int n = 0; n < 8; n++) acc[n] = MFMA16(xA1, fragW(sW, n * 16, 32, lane), acc[n]);
#pragma unroll
  for (int n = 0; n < 8; n++) {
    int d = n * 16 + col;
    float mul = cst[d], add = cst[128 + d];
#pragma unroll
    for (int r = 0; r < 4; r++) {
      float v = acc[n][r] * mul + add;
      v = v > 0.f ? v : 0.01f * v;
      putBf(sM, w * 16 + r0 + r, d, v);
    }
  }
  bf16x8 hA0 = fragM(sM, w * 16, 0, lane);   // own rows: same-wave, no barrier
  bf16x8 hA1 = fragM(sM, w * 16, 32, lane);
  bf16x8 hA2 = fragM(sM, w * 16, 64, lane);
  bf16x8 hA3 = fragM(sM, w * 16, 96, lane);
  __syncthreads();

  // ---- S6: commit c2
  stW(sW, t, sa, sb);
  __syncthreads();

  // ---- S7: accV = hA01 @ W1n[k<64]; issue c3 (W1n b)
  stG(wbf + 32768, 128, 64, t, sa, sb);
#pragma unroll
  for (int n = 0; n < 8; n++) acc[n] = zero;
#pragma unroll
  for (int n = 0; n < 8; n++) acc[n] = MFMA16(hA0, fragW(sW, n * 16, 0, lane), acc[n]);
#pragma unroll
  for (int n = 0; n < 8; n++) acc[n] = MFMA16(hA1, fragW(sW, n * 16, 32, lane), acc[n]);
  __syncthreads();

  // ---- S8: commit c3
  stW(sW, t, sa, sb);
  __syncthreads();

  // ---- S9: accV += hA23 @ W1n[k>=64]; write V1^T; issue c4 (W1s a)
  stG(wbf + 16384, 128, 0, t, sa, sb);
#pragma unroll
  for (int n = 0; n < 8; n++) acc[n] = MFMA16(hA2, fragW(sW, n * 16, 0, lane), acc[n]);
#pragma unroll
  for (int n = 0; n < 8; n++) acc[n] = MFMA16(hA3, fragW(sW, n * 16, 32, lane), acc[n]);
#pragma unroll
  for (int n = 0; n < 8; n++) {
    bf16x4 q = {(__bf16)acc[n][0], (__bf16)acc[n][1], (__bf16)acc[n][2], (__bf16)acc[n][3]};
    int d = n * 16 + col;
    *(bf16x4*)((char*)sM + d * 256 + (((w * 16 + r0) * 2) ^ ((d & 7) << 4))) = q;
  }
  __syncthreads();

  // ---- S10: commit c4; acc = Adj @ V1 (no weights)
  stW(sW, t, sa, sb);
#pragma unroll
  for (int n = 0; n < 8; n++) acc[n] = zero;
  {
    const float invRow = sInv[w * 16 + col];
    for (int kb = 0; kb < 4; kb++) {
      bf16x8 aF = adjFrag(sC, invRow, w * 16, kb * 32, lane);
#pragma unroll
      for (int n = 0; n < 8; n++)
        acc[n] = MFMA16(aF, fragM(sM, n * 16, kb * 32, lane), acc[n]);
    }
  }
  __syncthreads();

  // ---- S11: acc += hA01 @ W1s[k<64] (c4); issue c5 (W1s b) + mwr loads
  stG(wbf + 16384, 128, 64, t, sa, sb);
  float mwr[4];
#pragma unroll
  for (int r = 0; r < 4; r++) mwr[r] = mwt[(size_t)g * 128 + w * 16 + r0 + r];
#pragma unroll
  for (int n = 0; n < 8; n++) acc[n] = MFMA16(hA0, fragW(sW, n * 16, 0, lane), acc[n]);
#pragma unroll
  for (int n = 0; n < 8; n++) acc[n] = MFMA16(hA1, fragW(sW, n * 16, 32, lane), acc[n]);
  __syncthreads();

  // ---- S12: commit c5
  stW(sW, t, sa, sb);
  __syncthreads();

  // ---- S13: acc += hA23 @ W1s[k>=64]; BN1+leaky+mw -> h2 + pool; hA reload; issue c6 (Wa a)
  stG(wbf + 49152, 128, 0, t, sa, sb);
#pragma unroll
  for (int n = 0; n < 8; n++) acc[n] = MFMA16(hA2, fragW(sW, n * 16, 0, lane), acc[n]);
#pragma unroll
  for (int n = 0; n < 8; n++) acc[n] = MFMA16(hA3, fragW(sW, n * 16, 32, lane), acc[n]);
#pragma unroll
  for (int n = 0; n < 8; n++) {
    int d = n * 16 + col;
    float mul = cst[256 + d], add = cst[384 + d];
    float csum = 0.f;
#pragma unroll
    for (int r = 0; r < 4; r++) {
      float v = acc[n][r] * mul + add;
      v = v > 0.f ? v : 0.01f * v;
      v *= mwr[r];
      putBf(sM, w * 16 + r0 + r, d, v);
      csum += v;
    }
    csum += __shfl_xor(csum, 16);
    csum += __shfl_xor(csum, 32);
    if (lane < 16) atomicAdd(&sPool[d], csum);
  }
  hA0 = fragM(sM, w * 16, 0, lane);    // h2 own rows
  hA1 = fragM(sM, w * 16, 32, lane);
  hA2 = fragM(sM, w * 16, 64, lane);
  hA3 = fragM(sM, w * 16, 96, lane);
  __syncthreads();

  // ---- S14: commit c6
  stW(sW, t, sa, sb);
  __syncthreads();

  // ---- S15: accP = hA01 @ Wa[k<64]; issue c7 (Wa b)
  stG(wbf + 49152, 128, 64, t, sa, sb);
#pragma unroll
  for (int n = 0; n < 8; n++) acc[n] = zero;
#pragma unroll
  for (int n = 0; n < 8; n++) acc[n] = MFMA16(hA0, fragW(sW, n * 16, 0, lane), acc[n]);
#pragma unroll
  for (int n = 0; n < 8; n++) acc[n] = MFMA16(hA1, fragW(sW, n * 16, 32, lane), acc[n]);
  __syncthreads();

  // ---- S16: commit c7
  stW(sW, t, sa, sb);
  __syncthreads();

  // ---- S17: accP += hA23 @ Wa[k>=64]; +ba, leaky -> p own rows
#pragma unroll
  for (int n = 0; n < 8; n++) acc[n] = MFMA16(hA2, fragW(sW, n * 16, 0, lane), acc[n]);
#pragma unroll
  for (int n = 0; n < 8; n++) acc[n] = MFMA16(hA3, fragW(sW, n * 16, 32, lane), acc[n]);
#pragma unroll
  for (int n = 0; n < 8; n++) {
    int d = n * 16 + col;
    float bav = ba[d];
#pragma unroll
    for (int r = 0; r < 4; r++) {
      float v = acc[n][r] + bav;
      v = v > 0.f ? v : 0.01f * v;
      putBf(sM, w * 16 + r0 + r, d, v);
    }
  }
  __syncthreads();  // p complete for all rows

  // ---- S18: pair = sigmoid(pA@pB^T) -> sC; Ptr-read p blocks
  us4 rd[2][4];
  {
    unsigned short* sP = (unsigned short*)sC;
    f32x4 acc2[2] = {zero, zero};
    for (int kb = 0; kb < 128; kb += 32) {
#pragma unroll
      for (int i = 0; i < 2; i++) {
        int T = w * 2 + i;
        bf16x8 a = fragM(sM, (T >> 2) * 16, kb, lane);
        bf16x8 b = fragM(sM, 64 + (T & 3) * 16, kb, lane);
        acc2[i] = MFMA16(a, b, acc2[i]);
      }
    }
#pragma unroll
    for (int i = 0; i < 2; i++) {
      int T = w * 2 + i, mb = (T >> 2) * 16, nb = (T & 3) * 16;
#pragma unroll
      for (int r = 0; r < 4; r++) {
        float v = 1.f / (1.f + __expf(-acc2[i][r]));
        putP(sP, mb + r0 + r, nb + col, v);
        putP(sP + 4096, nb + col, mb + r0 + r, v);
      }
    }
#pragma unroll
    for (int b = 0; b < 2; b++) {
      int id = t + b * 512, R = id >> 5, C = id & 31;
#pragma unroll
      for (int j = 0; j < 4; j++) {
        int r = 4 * R + j;
        rd[b][j] = *(const us4*)((const char*)sM + r * 256 + ((C * 8) ^ ((r & 7) << 4)));
      }
    }
  }
  __syncthreads();  // all p reads done

  // ---- S19: Ptr-write p^T into sM
#pragma unroll
  for (int b = 0; b < 2; b++) {
    int id = t + b * 512, R = id >> 5, C = id & 31;
#pragma unroll
    for (int cc = 0; cc < 4; cc++) {
      us4 o = {rd[b][0][cc], rd[b][1][cc], rd[b][2][cc], rd[b][3][cc]};
      int r = 4 * C + cc;
      *(us4*)((char*)sM + r * 256 + ((R * 8) ^ ((r & 7) << 4))) = o;
    }
  }
  __syncthreads();

  // ---- S20: P7 deltas -> pool
  {
    const unsigned short* sP = (const unsigned short*)sC;
    const int isB = w >> 2;
    const int mr = (w & 3) * 16;
#pragma unroll
    for (int n = 0; n < 8; n++) acc[n] = zero;
    for (int kb = 0; kb < 64; kb += 32) {
      bf16x8 a = fragP(sP + (isB ? 4096 : 0), mr, kb, lane);
      int koff = isB ? kb : 64 + kb;
#pragma unroll
      for (int n = 0; n < 8; n++) {
        bf16x8 bfr = fragM(sM, n * 16, koff, lane);
        acc[n] = MFMA16(a, bfr, acc[n]);
      }
    }
#pragma unroll
    for (int n = 0; n < 8; n++) {
      int d = n * 16 + col;
      float csum = acc[n][0] + acc[n][1] + acc[n][2] + acc[n][3];
      csum += __shfl_xor(csum, 16);
      csum += __shfl_xor(csum, 32);
      if (lane < 16) atomicAdd(&sPool[d], csum);
    }
  }
  __syncthreads();

  // ---- S21: readout
  if (t < 128) sPool[t] *= (1.f / 128.f);
  __syncthreads();
  {
    int d = t >> 2, q = t & 3;
    const float* row = wr0t + d * 128 + q * 32;
    float s = 0.f;
#pragma unroll
    for (int j = 0; j < 32; j++) s += sPool[q * 32 + j] * row[j];
    s += __shfl_xor(s, 1);
    s += __shfl_xor(s, 2);
    if (q == 0) { s += br0[d]; sV1[d] = s > 0.f ? s : 0.01f * s; }
  }
  __syncthreads();
  {
    int d = t >> 2, q = t & 3;
    const float* row = wr1t + d * 128 + q * 32;
    float s = 0.f;
#pragma unroll
    for (int j = 0; j < 32; j++) s += sV1[q * 32 + j] * row[j];
    s += __shfl_xor(s, 1);
    s += __shfl_xor(s, 2);
    if (q == 0) { s += br1[d]; sPool[d] = s > 0.f ? s : 0.01f * s; }
  }
  __syncthreads();
  if (t < 128) atomicAdd(&sOut, sPool[t] * Wout[t]);
  __syncthreads();
  if (t == 0) out[g] = sOut + bout[0];
}

extern "C" void kernel_launch(void* const* d_in, const int* in_sizes, int n_in,
                              void* d_out, int out_size, void* d_ws, size_t ws_size,
                              hipStream_t stream) {
  const float* x     = (const float*)d_in[0];
  const float* mwt   = (const float*)d_in[1];
  const float* Wc0s  = (const float*)d_in[2];
  const float* Wc0n  = (const float*)d_in[3];
  const float* bc0   = (const float*)d_in[4];
  const float* g0    = (const float*)d_in[5];
  const float* b0    = (const float*)d_in[6];
  const float* m0    = (const float*)d_in[7];
  const float* v0    = (const float*)d_in[8];
  const float* Wc1s  = (const float*)d_in[9];
  const float* Wc1n  = (const float*)d_in[10];
  const float* bc1   = (const float*)d_in[11];
  const float* g1    = (const float*)d_in[12];
  const float* b1    = (const float*)d_in[13];
  const float* m1    = (const float*)d_in[14];
  const float* v1    = (const float*)d_in[15];
  const float* Wa    = (const float*)d_in[16];
  const float* ba    = (const float*)d_in[17];
  const float* Wr0   = (const float*)d_in[18];
  const float* br0   = (const float*)d_in[19];
  const float* Wr1   = (const float*)d_in[20];
  const float* br1   = (const float*)d_in[21];
  const float* Wout  = (const float*)d_in[22];
  const float* bout  = (const float*)d_in[23];
  const int*   ei    = (const int*)d_in[24];

  unsigned short* wbf = (unsigned short*)d_ws;                 // 131072 B
  float* cst  = (float*)((char*)d_ws + 131072);                // 2048 B
  float* wr0t = (float*)((char*)d_ws + 133120);                // 65536 B
  float* wr1t = (float*)((char*)d_ws + 198656);                // 65536 B

  prep_kernel<<<dim3(225), dim3(256), 0, stream>>>(Wc0s, Wc0n, Wc1s, Wc1n, Wa,
                                                   bc0, g0, b0, m0, v0,
                                                   bc1, g1, b1, m1, v1,
                                                   Wr0, Wr1, wbf, cst, wr0t, wr1t);
  gnn_fused<<<dim3(2048), dim3(512), 0, stream>>>(x, mwt, ei, wbf, cst, ba,
                                                  wr0t, br0, wr1t, br1, Wout, bout,
                                                  (float*)d_out);
}

// Round 7
// 161.519 us; speedup vs baseline: 2.3199x; 1.0107x over previous
//
#include <hip/hip_runtime.h>

#define N_EDGES_C 1048576

typedef __attribute__((ext_vector_type(8))) __bf16 bf16x8;
typedef __attribute__((ext_vector_type(4))) __bf16 bf16x4;
typedef __attribute__((ext_vector_type(4))) float f32x4;
typedef __attribute__((ext_vector_type(4))) unsigned int u32x4;

#define MFMA16(a,b,c) __builtin_amdgcn_mfma_f32_16x16x32_bf16((a),(b),(c),0,0,0)

__device__ __forceinline__ unsigned short f2bf(float f) {
  unsigned int u = __builtin_bit_cast(unsigned int, f);
  u = (u + 0x7fffu + ((u >> 16) & 1u)) >> 16;
  return (unsigned short)u;
}
__device__ __forceinline__ float bf2f(unsigned short h) {
  unsigned int u = ((unsigned int)h) << 16;
  return __builtin_bit_cast(float, u);
}

// swizzled 128x128 bf16 LDS tile (row stride 256B, byte ^= (row&7)<<4)
__device__ __forceinline__ bf16x8 fragM(const unsigned short* sM, int row, int kb, int lane) {
  int r = row + (lane & 15);
  int cb = (kb + ((lane >> 4) << 3)) * 2;
  return *(const bf16x8*)((const char*)sM + r * 256 + (cb ^ ((r & 7) << 4)));
}
__device__ __forceinline__ void putBf(unsigned short* sM, int r, int c, float v) {
  *(__bf16*)((char*)sM + r * 256 + ((c * 2) ^ ((r & 7) << 4))) = (__bf16)v;
}
// Adj counts: u8 [128][128], row stride 128B, byte col ^= (row&7)<<3 (register-only decode)
__device__ __forceinline__ bf16x8 adjFrag(const unsigned char* sCc, float inv,
                                          int mBase, int kb, int lane) {
  int m = mBase + (lane & 15);
  int c = (kb + ((lane >> 4) << 3)) ^ ((m & 7) << 3);
  const unsigned int* p = (const unsigned int*)(sCc + m * 128 + c);
  unsigned int w0 = p[0], w1 = p[1];
  bf16x8 r;
#pragma unroll
  for (int i = 0; i < 4; i++) {
    r[i]     = (__bf16)((float)((w0 >> (8 * i)) & 0xffu) * inv);
    r[4 + i] = (__bf16)((float)((w1 >> (8 * i)) & 0xffu) * inv);
  }
  return r;
}

// K=32 weight chunk ring buffer: [128 rows][32 k] u16 = 8KB, row 64B.
// phys 16B slot = (ks + r + (r>>2)) & 3  -> conflict-free reads & writes.
__device__ __forceinline__ u32x4 stG32(const unsigned short* src, int KS, int ko, int t) {
  int row = t >> 2, ks = t & 3;
  return *(const u32x4*)(src + row * KS + ko + ks * 8);
}
__device__ __forceinline__ void stW32(unsigned short* buf, int t, u32x4 v) {
  int row = t >> 2, ks = t & 3;
  int slot = (ks + row + (row >> 2)) & 3;
  *(u32x4*)((char*)buf + row * 64 + slot * 16) = v;
}
__device__ __forceinline__ bf16x8 fragW32(const unsigned short* buf, int nc, int lane) {
  int r = nc + (lane & 15);
  int ks = lane >> 4;
  int slot = (ks + r + (r >> 2)) & 3;
  return *(const bf16x8*)((const char*)buf + r * 64 + slot * 16);
}

// ---------------- prep: bf16-transpose weights + fold BN + transpose readout W ----------------
__global__ void prep_kernel(const float* __restrict__ Wc0s, const float* __restrict__ Wc0n,
                            const float* __restrict__ Wc1s, const float* __restrict__ Wc1n,
                            const float* __restrict__ Wa,
                            const float* __restrict__ bc0, const float* __restrict__ g0,
                            const float* __restrict__ b0, const float* __restrict__ m0,
                            const float* __restrict__ v0,
                            const float* __restrict__ bc1, const float* __restrict__ g1,
                            const float* __restrict__ b1, const float* __restrict__ m1,
                            const float* __restrict__ v1,
                            const float* __restrict__ Wr0, const float* __restrict__ Wr1,
                            unsigned short* __restrict__ wbf, float* __restrict__ cst,
                            float* __restrict__ wr0t, float* __restrict__ wr1t) {
  int t = blockIdx.x * blockDim.x + threadIdx.x;
  if (t < 8192) {                       // 64x128 -> [d][f]
    int d = t >> 6, f = t & 63;
    wbf[t]        = f2bf(Wc0s[f * 128 + d]);
    wbf[8192 + t] = f2bf(Wc0n[f * 128 + d]);
  } else if (t < 24576) {               // 128x128 -> [d][k]
    int i = t - 8192;
    int d = i >> 7, k = i & 127;
    wbf[16384 + i] = f2bf(Wc1s[k * 128 + d]);
    wbf[32768 + i] = f2bf(Wc1n[k * 128 + d]);
    wbf[49152 + i] = f2bf(Wa[k * 128 + d]);
  } else if (t < 24704) {
    int d = t - 24576;
    float s0 = g0[d] * rsqrtf(v0[d] + 1e-5f);
    cst[d]       = s0;
    cst[128 + d] = (bc0[d] - m0[d]) * s0 + b0[d];
    float s1 = g1[d] * rsqrtf(v1[d] + 1e-5f);
    cst[256 + d] = s1;
    cst[384 + d] = (bc1[d] - m1[d]) * s1 + b1[d];
  } else if (t < 57472) {               // readout weights f32 transpose
    int i = t - 24704;
    int which = i >> 14;
    int k = i & 16383;
    int d = k >> 7, j = k & 127;
    float v = (which ? Wr1 : Wr0)[j * 128 + d];
    (which ? wr1t : wr0t)[k] = v;
  }
}

// ---------------- fused per-graph kernel: 1 block = 1 graph, ~75KB LDS, 2 blocks/CU ----------------
__global__ __launch_bounds__(512, 4)
void gnn_fused(const float* __restrict__ x, const float* __restrict__ mwt,
               const int* __restrict__ ei,
               const unsigned short* __restrict__ wbf, const float* __restrict__ cst,
               const float* __restrict__ ba,
               const float* __restrict__ wr0t, const float* __restrict__ br0,
               const float* __restrict__ wr1t, const float* __restrict__ br1,
               const float* __restrict__ Wout, const float* __restrict__ bout,
               float* __restrict__ out) {
  __shared__ unsigned short sM[128 * 128];   // 32KB: x / V^T / h / p (swizzled)
  __shared__ unsigned char  sC[128 * 128];   // 16KB: Adj u8 counts
  __shared__ unsigned short sW[3][4096];     // 3 x 8KB weight chunk ring
  __shared__ float sInv[128];
  __shared__ float sPool[128];
  __shared__ float sV1[128];                 // rowsum[0:64] / colsum[64:128], later readout tmp
  __shared__ float sOut;

  const int g = blockIdx.x;
  const int t = threadIdx.x;
  const int lane = t & 63;
  const int w = t >> 6;              // wave 0..7
  const int col = lane & 15;
  const int r0 = (lane >> 4) << 2;
  const f32x4 zero = {0.f, 0.f, 0.f, 0.f};
  u32x4 st0, st1;                    // in-flight stage regs

  // ---- Ph0: issue c0,c1,c2; zero; x -> sM
  st0 = stG32(wbf + 8192, 64, 0, t);   // c0 = W0n k0-31
  st1 = stG32(wbf + 8192, 64, 32, t);  // c1 = W0n k32-63
  u32x4 st2 = stG32(wbf, 64, 0, t);    // c2 = W0s k0-31
  {
    unsigned int* c32 = (unsigned int*)sC;
    for (int i = t; i < 4096; i += 512) c32[i] = 0u;
    if (t < 128) { sPool[t] = 0.f; sV1[t] = 0.f; }
    if (t == 0) sOut = 0.f;
  }
  {
    const float4* xg = (const float4*)(x + (size_t)g * 8192);
#pragma unroll
    for (int i = 0; i < 4; i++) {
      int vi = t + i * 512;
      float4 v = xg[vi];
      int node = vi >> 4;
      int f = (vi & 15) * 4;
      bf16x4 q = {(__bf16)v.x, (__bf16)v.y, (__bf16)v.z, (__bf16)v.w};
      *(bf16x4*)((char*)sM + node * 256 + ((f * 2) ^ ((node & 7) << 4))) = q;
    }
  }
  __syncthreads();

  // ---- Ph1: hist; commit c0,c1,c2; xA preload
  {
    int e = g * 512 + t;
    int ls_ = ei[e] & 127;
    int ld_ = ei[N_EDGES_C + e] & 127;
    int cb = ls_ ^ ((ld_ & 7) << 3);
    int idx = ld_ * 128 + cb;
    atomicAdd((unsigned int*)(sC + (idx & ~3)), 1u << ((idx & 3) * 8));
  }
  stW32(sW[0], t, st0);
  stW32(sW[1], t, st1);
  stW32(sW[2], t, st2);
  bf16x8 xA0 = fragM(sM, w * 16, 0, lane);
  bf16x8 xA1 = fragM(sM, w * 16, 32, lane);
  __syncthreads();

  f32x4 acc[8];

  // ---- Ph2: invdeg; issue c3,c4; V0 = xA0@c0 + xA1@c1; write V0^T
  {
    int row = t >> 2, q = t & 3;
    const unsigned int* rp = (const unsigned int*)(sC + row * 128) + q * 8;
    int ssum = 0;
#pragma unroll
    for (int i = 0; i < 8; i++) {
      unsigned int v = rp[i];
      ssum += (int)(v & 0xff) + (int)((v >> 8) & 0xff) + (int)((v >> 16) & 0xff) + (int)(v >> 24);
    }
    ssum += __shfl_xor(ssum, 1);
    ssum += __shfl_xor(ssum, 2);
    if (q == 0) sInv[row] = 1.f / (float)(ssum > 1 ? ssum : 1);
  }
  st0 = stG32(wbf, 64, 32, t);           // c3 = W0s k32-63 -> ring0
  st1 = stG32(wbf + 32768, 128, 0, t);   // c4 = W1n k0 -> ring1
#pragma unroll
  for (int n = 0; n < 8; n++) acc[n] = zero;
#pragma unroll
  for (int n = 0; n < 8; n++) acc[n] = MFMA16(xA0, fragW32(sW[0], n * 16, lane), acc[n]);
#pragma unroll
  for (int n = 0; n < 8; n++) acc[n] = MFMA16(xA1, fragW32(sW[1], n * 16, lane), acc[n]);
#pragma unroll
  for (int n = 0; n < 8; n++) {  // V0^T[d][node]
    bf16x4 q = {(__bf16)acc[n][0], (__bf16)acc[n][1], (__bf16)acc[n][2], (__bf16)acc[n][3]};
    int d = n * 16 + col;
    *(bf16x4*)((char*)sM + d * 256 + (((w * 16 + r0) * 2) ^ ((d & 7) << 4))) = q;
  }
  __syncthreads();

  // ---- Ph3: commit c3,c4; issue c5; acc = Adj@V0 + xA0@c2
  stW32(sW[0], t, st0);
  stW32(sW[1], t, st1);
  st0 = stG32(wbf + 32768, 128, 32, t);  // c5 = W1n k32 -> ring2
  const float invRow = sInv[w * 16 + col];
#pragma unroll
  for (int n = 0; n < 8; n++) acc[n] = zero;
#pragma unroll
  for (int n = 0; n < 8; n++) acc[n] = MFMA16(xA0, fragW32(sW[2], n * 16, lane), acc[n]);
  for (int kb = 0; kb < 4; kb++) {
    bf16x8 aF = adjFrag(sC, invRow, w * 16, kb * 32, lane);
#pragma unroll
    for (int n = 0; n < 8; n++)
      acc[n] = MFMA16(aF, fragM(sM, n * 16, kb * 32, lane), acc[n]);
  }
  __syncthreads();

  // ---- Ph4: commit c5; issue c6; acc += xA1@c3; BN0 epi -> h1; hA preload
  stW32(sW[2], t, st0);
  st1 = stG32(wbf + 32768, 128, 64, t);  // c6 = W1n k64 -> ring0
#pragma unroll
  for (int n = 0; n < 8; n++) acc[n] = MFMA16(xA1, fragW32(sW[0], n * 16, lane), acc[n]);
#pragma unroll
  for (int n = 0; n < 8; n++) {
    int d = n * 16 + col;
    float mul = cst[d], add = cst[128 + d];
#pragma unroll
    for (int r = 0; r < 4; r++) {
      float v = acc[n][r] * mul + add;
      v = v > 0.f ? v : 0.01f * v;
      putBf(sM, w * 16 + r0 + r, d, v);
    }
  }
  bf16x8 hA0 = fragM(sM, w * 16, 0, lane);   // own rows: same-wave RAW ok
  bf16x8 hA1 = fragM(sM, w * 16, 32, lane);
  bf16x8 hA2 = fragM(sM, w * 16, 64, lane);
  bf16x8 hA3 = fragM(sM, w * 16, 96, lane);
  __syncthreads();

  // ---- Ph5: commit c6; issue c7; accV = hA0@c4
  stW32(sW[0], t, st1);
  st0 = stG32(wbf + 32768, 128, 96, t);  // c7 = W1n k96 -> ring1
#pragma unroll
  for (int n = 0; n < 8; n++) acc[n] = zero;
#pragma unroll
  for (int n = 0; n < 8; n++) acc[n] = MFMA16(hA0, fragW32(sW[1], n * 16, lane), acc[n]);
  __syncthreads();

  // ---- Ph6: commit c7; issue c8; accV += hA1@c5
  stW32(sW[1], t, st0);
  st1 = stG32(wbf + 16384, 128, 0, t);   // c8 = W1s k0 -> ring2
#pragma unroll
  for (int n = 0; n < 8; n++) acc[n] = MFMA16(hA1, fragW32(sW[2], n * 16, lane), acc[n]);
  __syncthreads();

  // ---- Ph7: commit c8; issue c9; accV += hA2@c6
  stW32(sW[2], t, st1);
  st0 = stG32(wbf + 16384, 128, 32, t);  // c9 = W1s k32 -> ring0
#pragma unroll
  for (int n = 0; n < 8; n++) acc[n] = MFMA16(hA2, fragW32(sW[0], n * 16, lane), acc[n]);
  __syncthreads();

  // ---- Ph8: commit c9; issue c10; accV += hA3@c7; write V1^T
  stW32(sW[0], t, st0);
  st1 = stG32(wbf + 16384, 128, 64, t);  // c10 = W1s k64 -> ring1
#pragma unroll
  for (int n = 0; n < 8; n++) acc[n] = MFMA16(hA3, fragW32(sW[1], n * 16, lane), acc[n]);
#pragma unroll
  for (int n = 0; n < 8; n++) {
    bf16x4 q = {(__bf16)acc[n][0], (__bf16)acc[n][1], (__bf16)acc[n][2], (__bf16)acc[n][3]};
    int d = n * 16 + col;
    *(bf16x4*)((char*)sM + d * 256 + (((w * 16 + r0) * 2) ^ ((d & 7) << 4))) = q;
  }
  __syncthreads();

  // ---- Ph9: commit c10; issue c11; acc = Adj@V1
  stW32(sW[1], t, st1);
  st0 = stG32(wbf + 16384, 128, 96, t);  // c11 = W1s k96 -> ring2
#pragma unroll
  for (int n = 0; n < 8; n++) acc[n] = zero;
  for (int kb = 0; kb < 4; kb++) {
    bf16x8 aF = adjFrag(sC, invRow, w * 16, kb * 32, lane);
#pragma unroll
    for (int n = 0; n < 8; n++)
      acc[n] = MFMA16(aF, fragM(sM, n * 16, kb * 32, lane), acc[n]);
  }
  __syncthreads();

  // ---- Ph10: issue c12; acc += hA0@c8   (no commit: ring2 busy until c8 read)
  st1 = stG32(wbf + 49152, 128, 0, t);   // c12 = Wa k0 -> ring0
#pragma unroll
  for (int n = 0; n < 8; n++) acc[n] = MFMA16(hA0, fragW32(sW[2], n * 16, lane), acc[n]);
  __syncthreads();

  // ---- Ph11: commit c11; issue c13; acc += hA1@c9; mwr preload
  stW32(sW[2], t, st0);
  st0 = stG32(wbf + 49152, 128, 32, t);  // c13 = Wa k32 -> ring1
  float mwr[4];
#pragma unroll
  for (int r = 0; r < 4; r++) mwr[r] = mwt[(size_t)g * 128 + w * 16 + r0 + r];
#pragma unroll
  for (int n = 0; n < 8; n++) acc[n] = MFMA16(hA1, fragW32(sW[0], n * 16, lane), acc[n]);
  __syncthreads();

  // ---- Ph12: commit c12; issue c14; acc += hA2@c10
  stW32(sW[0], t, st1);
  st1 = stG32(wbf + 49152, 128, 64, t);  // c14 = Wa k64 -> ring2
#pragma unroll
  for (int n = 0; n < 8; n++) acc[n] = MFMA16(hA2, fragW32(sW[1], n * 16, lane), acc[n]);
  __syncthreads();

  // ---- Ph13: commit c13; issue c15; acc += hA3@c11; BN1 epi -> h2 + pool; hA reload
  stW32(sW[1], t, st0);
  st0 = stG32(wbf + 49152, 128, 96, t);  // c15 = Wa k96 -> ring0
#pragma unroll
  for (int n = 0; n < 8; n++) acc[n] = MFMA16(hA3, fragW32(sW[2], n * 16, lane), acc[n]);
#pragma unroll
  for (int n = 0; n < 8; n++) {
    int d = n * 16 + col;
    float mul = cst[256 + d], add = cst[384 + d];
    float csum = 0.f;
#pragma unroll
    for (int r = 0; r < 4; r++) {
      float v = acc[n][r] * mul + add;
      v = v > 0.f ? v : 0.01f * v;
      v *= mwr[r];
      putBf(sM, w * 16 + r0 + r, d, v);
      csum += v;
    }
    csum += __shfl_xor(csum, 16);
    csum += __shfl_xor(csum, 32);
    if (lane < 16) atomicAdd(&sPool[d], csum);
  }
  hA0 = fragM(sM, w * 16, 0, lane);    // h2 own rows
  hA1 = fragM(sM, w * 16, 32, lane);
  hA2 = fragM(sM, w * 16, 64, lane);
  hA3 = fragM(sM, w * 16, 96, lane);
  __syncthreads();

  // ---- Ph14: commit c14; accP = hA0@c12
  stW32(sW[2], t, st1);
#pragma unroll
  for (int n = 0; n < 8; n++) acc[n] = zero;
#pragma unroll
  for (int n = 0; n < 8; n++) acc[n] = MFMA16(hA0, fragW32(sW[0], n * 16, lane), acc[n]);
  __syncthreads();

  // ---- Ph15: commit c15; accP += hA1@c13
  stW32(sW[0], t, st0);
#pragma unroll
  for (int n = 0; n < 8; n++) acc[n] = MFMA16(hA1, fragW32(sW[1], n * 16, lane), acc[n]);
  __syncthreads();

  // ---- Ph16: accP += hA2@c14
#pragma unroll
  for (int n = 0; n < 8; n++) acc[n] = MFMA16(hA2, fragW32(sW[2], n * 16, lane), acc[n]);
  __syncthreads();

  // ---- Ph17: accP += hA3@c15; +ba leaky -> p own rows
#pragma unroll
  for (int n = 0; n < 8; n++) acc[n] = MFMA16(hA3, fragW32(sW[0], n * 16, lane), acc[n]);
#pragma unroll
  for (int n = 0; n < 8; n++) {
    int d = n * 16 + col;
    float bav = ba[d];
#pragma unroll
    for (int r = 0; r < 4; r++) {
      float v = acc[n][r] + bav;
      v = v > 0.f ? v : 0.01f * v;
      putBf(sM, w * 16 + r0 + r, d, v);
    }
  }
  __syncthreads();  // p complete for all rows

  // ---- Ph18: pair tiles -> sigmoid -> row/col sums (pair never stored)
  // rowsum[m] -> sV1[m], colsum[n] -> sV1[64+n]
  {
    f32x4 acc2[2] = {zero, zero};
    for (int kb = 0; kb < 128; kb += 32) {
#pragma unroll
      for (int i = 0; i < 2; i++) {
        int T = w * 2 + i;
        bf16x8 a = fragM(sM, (T >> 2) * 16, kb, lane);       // pA rows mb..mb+15
        bf16x8 b = fragM(sM, 64 + (T & 3) * 16, kb, lane);   // pB rows nb..nb+15
        acc2[i] = MFMA16(a, b, acc2[i]);
      }
    }
#pragma unroll
    for (int i = 0; i < 2; i++) {
      int T = w * 2 + i, mb = (T >> 2) * 16, nb = (T & 3) * 16;
      float s0 = 1.f / (1.f + __expf(-acc2[i][0]));
      float s1 = 1.f / (1.f + __expf(-acc2[i][1]));
      float s2 = 1.f / (1.f + __expf(-acc2[i][2]));
      float s3 = 1.f / (1.f + __expf(-acc2[i][3]));
      // colsum partial: 4 rows, same col
      atomicAdd(&sV1[64 + nb + col], s0 + s1 + s2 + s3);
      // rowsum: butterfly over the 16 col lanes (lane bits 0-3)
#pragma unroll
      for (int m = 1; m < 16; m <<= 1) {
        s0 += __shfl_xor(s0, m);
        s1 += __shfl_xor(s1, m);
        s2 += __shfl_xor(s2, m);
        s3 += __shfl_xor(s3, m);
      }
      if (col < 4) {
        float v = col == 0 ? s0 : (col == 1 ? s1 : (col == 2 ? s2 : s3));
        atomicAdd(&sV1[mb + r0 + col], v);
      }
    }
  }
  __syncthreads();

  // ---- Ph19: delta pool: sPool[d] += sum_node u[node]*p[node][d]
  // u[node<64] = rowsum (weights pA), u[node>=64] = colsum (weights pB)
  {
    int d = t & 127, q = t >> 7;       // all lanes in a wave share q -> broadcast u
    float s = 0.f;
#pragma unroll
    for (int i = 0; i < 32; i++) {
      int node = q * 32 + i;
      float u = sV1[node];
      float pv = bf2f(*(const unsigned short*)((const char*)sM + node * 256 +
                                               ((2 * d) ^ ((node & 7) << 4))));
      s += u * pv;
    }
    atomicAdd(&sPool[d], s);
  }
  __syncthreads();

  // ---- readout
  if (t < 128) sPool[t] *= (1.f / 128.f);
  __syncthreads();
  {
    int d = t >> 2, q = t & 3;
    const float* row = wr0t + d * 128 + q * 32;
    float s = 0.f;
#pragma unroll
    for (int j = 0; j < 32; j++) s += sPool[q * 32 + j] * row[j];
    s += __shfl_xor(s, 1);
    s += __shfl_xor(s, 2);
    if (q == 0) { s += br0[d]; sV1[d] = s > 0.f ? s : 0.01f * s; }
  }
  __syncthreads();
  {
    int d = t >> 2, q = t & 3;
    const float* row = wr1t + d * 128 + q * 32;
    float s = 0.f;
#pragma unroll
    for (int j = 0; j < 32; j++) s += sV1[q * 32 + j] * row[j];
    s += __shfl_xor(s, 1);
    s += __shfl_xor(s, 2);
    if (q == 0) { s += br1[d]; sPool[d] = s > 0.f ? s : 0.01f * s; }
  }
  __syncthreads();
  if (t < 128) atomicAdd(&sOut, sPool[t] * Wout[t]);
  __syncthreads();
  if (t == 0) out[g] = sOut + bout[0];
}

extern "C" void kernel_launch(void* const* d_in, const int* in_sizes, int n_in,
                              void* d_out, int out_size, void* d_ws, size_t ws_size,
                              hipStream_t stream) {
  const float* x     = (const float*)d_in[0];
  const float* mwt   = (const float*)d_in[1];
  const float* Wc0s  = (const float*)d_in[2];
  const float* Wc0n  = (const float*)d_in[3];
  const float* bc0   = (const float*)d_in[4];
  const float* g0    = (const float*)d_in[5];
  const float* b0    = (const float*)d_in[6];
  const float* m0    = (const float*)d_in[7];
  const float* v0    = (const float*)d_in[8];
  const float* Wc1s  = (const float*)d_in[9];
  const float* Wc1n  = (const float*)d_in[10];
  const float* bc1   = (const float*)d_in[11];
  const float* g1    = (const float*)d_in[12];
  const float* b1    = (const float*)d_in[13];
  const float* m1    = (const float*)d_in[14];
  const float* v1    = (const float*)d_in[15];
  const float* Wa    = (const float*)d_in[16];
  const float* ba    = (const float*)d_in[17];
  const float* Wr0   = (const float*)d_in[18];
  const float* br0   = (const float*)d_in[19];
  const float* Wr1   = (const float*)d_in[20];
  const float* br1   = (const float*)d_in[21];
  const float* Wout  = (const float*)d_in[22];
  const float* bout  = (const float*)d_in[23];
  const int*   ei    = (const int*)d_in[24];

  unsigned short* wbf = (unsigned short*)d_ws;                 // 131072 B
  float* cst  = (float*)((char*)d_ws + 131072);                // 2048 B
  float* wr0t = (float*)((char*)d_ws + 133120);                // 65536 B
  float* wr1t = (float*)((char*)d_ws + 198656);                // 65536 B

  prep_kernel<<<dim3(225), dim3(256), 0, stream>>>(Wc0s, Wc0n, Wc1s, Wc1n, Wa,
                                                   bc0, g0, b0, m0, v0,
                                                   bc1, g1, b1, m1, v1,
                                                   Wr0, Wr1, wbf, cst, wr0t, wr1t);
  gnn_fused<<<dim3(2048), dim3(512), 0, stream>>>(x, mwt, ei, wbf, cst, ba,
                                                  wr0t, br0, wr1t, br1, Wout, bout,
                                                  (float*)d_out);
}